// Round 4
// baseline (144.341 us; speedup 1.0000x reference)
//
#include <hip/hip_runtime.h>
#include <string.h>

// Problem constants (match reference)
static constexpr int H  = 1024, W = 1024, B = 8, C = 4, K = 3;
static constexpr int HW = H * W;
static constexpr int F  = (H / 2) * (W / 2);   // 262144 filled
static constexpr int U  = HW - F;              // 786432 unfilled
static constexpr int NP = B * C;               // 32 planes

// bf16 helpers (RNE round)
__device__ inline unsigned short f2bf(float f) {
    unsigned u = __float_as_uint(f);
    u += 0x7fffu + ((u >> 16) & 1u);
    return (unsigned short)(u >> 16);
}
__device__ inline float bf_lo(unsigned v) { return __uint_as_float(v << 16); }
__device__ inline float bf_hi(unsigned v) { return __uint_as_float(v & 0xffff0000u); }

// non-temporal helpers
__device__ inline void nt_store_f2(float2 v, float2* p) {
    double d;
    memcpy(&d, &v, 8);
    __builtin_nontemporal_store(d, reinterpret_cast<double*>(p));
}
__device__ inline int2 nt_load_i2(const int* p) {
    long long l = __builtin_nontemporal_load(reinterpret_cast<const long long*>(p));
    int2 r; memcpy(&r, &l, 8); return r;
}
__device__ inline float2 nt_load_f2(const float* p) {
    double d = __builtin_nontemporal_load(reinterpret_cast<const double*>(p));
    float2 r; memcpy(&r, &d, 8); return r;
}

// ---------------------------------------------------------------------------
// Kernel 1: build T[f][32] bf16 (64 B row). No out writes.
// ---------------------------------------------------------------------------
__global__ void build_T_kernel(const float2* __restrict__ src2,
                               uint4* __restrict__ T) {
    int f = blockIdx.x * blockDim.x + threadIdx.x;
    if (f >= F) return;
    int r2 = f >> 9;
    int c2 = f & 511;
    int base = r2 * W + c2;                    // float2 index within a plane
    unsigned packed[NP / 2];
    #pragma unroll
    for (int p = 0; p < NP; p += 2) {
        float2 v0 = src2[(size_t)p * (HW / 2) + base];
        float2 v1 = src2[(size_t)(p + 1) * (HW / 2) + base];
        packed[p / 2] = (unsigned)f2bf(v0.x) | ((unsigned)f2bf(v1.x) << 16);
    }
    uint4* row = T + (size_t)f * 4;
    #pragma unroll
    for (int c = 0; c < 4; ++c)
        row[c] = make_uint4(packed[4*c], packed[4*c+1], packed[4*c+2], packed[4*c+3]);
}

// ---------------------------------------------------------------------------
// Kernel 2a: even rows. One thread per (filled, unfilled) column pair.
// t = blk*512 + rem ; image row = 2*blk, cols (2*rem, 2*rem+1).
// u = blk*1536 + rem ; left-neighbor filled index f == t (sequential T read).
// Writes float2 (copy, interp) — even-row lines fully written here.
// ---------------------------------------------------------------------------
__global__ void fill_even_kernel(const int*   __restrict__ idx,
                                 const float* __restrict__ dist,
                                 const uint4* __restrict__ T,
                                 float2* __restrict__ out2) {
    int t = blockIdx.x * blockDim.x + threadIdx.x;
    if (t >= F) return;                        // F = 512*512 even-row pairs
    int blk = t >> 9;
    int rem = t & 511;
    int u = blk * 1536 + rem;

    int i0 = __builtin_nontemporal_load(idx + 3*u + 0);
    int i1 = __builtin_nontemporal_load(idx + 3*u + 1);
    int i2 = __builtin_nontemporal_load(idx + 3*u + 2);
    float w0 = 1.0f / __builtin_nontemporal_load(dist + 3*u + 0);
    float w1 = 1.0f / __builtin_nontemporal_load(dist + 3*u + 1);
    float w2 = 1.0f / __builtin_nontemporal_load(dist + 3*u + 2);
    float inv = 1.0f / (w0 + w1 + w2);
    w0 *= inv; w1 *= inv; w2 *= inv;

    const uint4* r0 = T + (size_t)i0 * 4;
    const uint4* r1 = T + (size_t)i1 * 4;
    const uint4* r2 = T + (size_t)i2 * 4;
    const uint4* rs = T + (size_t)t  * 4;      // self (left filled neighbor)

    // float2 index: plane p base = p*HW/2, row 2*blk base = blk*W, col pair = rem
    size_t obase = (size_t)blk * W + rem;
    #pragma unroll
    for (int c = 0; c < 4; ++c) {
        uint4 a = r0[c], b = r1[c], d = r2[c], s = rs[c];
        unsigned av[4] = {a.x, a.y, a.z, a.w};
        unsigned bv[4] = {b.x, b.y, b.z, b.w};
        unsigned dv[4] = {d.x, d.y, d.z, d.w};
        unsigned sv[4] = {s.x, s.y, s.z, s.w};
        #pragma unroll
        for (int j = 0; j < 4; ++j) {
            int p = c * 8 + j * 2;
            float2 lo = make_float2(bf_lo(sv[j]),
                                    w0*bf_lo(av[j]) + w1*bf_lo(bv[j]) + w2*bf_lo(dv[j]));
            float2 hi = make_float2(bf_hi(sv[j]),
                                    w0*bf_hi(av[j]) + w1*bf_hi(bv[j]) + w2*bf_hi(dv[j]));
            nt_store_f2(lo, out2 + (size_t)p       * (HW/2) + obase);
            nt_store_f2(hi, out2 + (size_t)(p + 1) * (HW/2) + obase);
        }
    }
}

// ---------------------------------------------------------------------------
// Kernel 2b: odd rows. One thread per pixel PAIR (cols 2*rem2, 2*rem2+1).
// u0 = blk*1536 + 512 + 2*rem2, u1 = u0+1. Writes float2 (interp, interp).
// ---------------------------------------------------------------------------
__global__ void fill_odd_kernel(const int*   __restrict__ idx,
                                const float* __restrict__ dist,
                                const uint4* __restrict__ T,
                                float2* __restrict__ out2) {
    int t = blockIdx.x * blockDim.x + threadIdx.x;
    if (t >= F) return;                        // 512*512 odd-row pairs
    int blk  = t >> 9;
    int rem2 = t & 511;
    int u0 = blk * 1536 + 512 + 2 * rem2;

    const int*   ip = idx  + (size_t)3 * u0;   // 6 consecutive ints (8B aligned)
    const float* dp = dist + (size_t)3 * u0;
    int2 iA = nt_load_i2(ip);
    int2 iB = nt_load_i2(ip + 2);
    int2 iC = nt_load_i2(ip + 4);
    float2 dA = nt_load_f2(dp);
    float2 dB = nt_load_f2(dp + 2);
    float2 dC = nt_load_f2(dp + 4);

    float w00 = 1.0f / dA.x, w01 = 1.0f / dA.y, w02 = 1.0f / dB.x;
    float w10 = 1.0f / dB.y, w11 = 1.0f / dC.x, w12 = 1.0f / dC.y;
    float inv0 = 1.0f / (w00 + w01 + w02);
    float inv1 = 1.0f / (w10 + w11 + w12);
    w00 *= inv0; w01 *= inv0; w02 *= inv0;
    w10 *= inv1; w11 *= inv1; w12 *= inv1;

    const uint4* r0 = T + (size_t)iA.x * 4;
    const uint4* r1 = T + (size_t)iA.y * 4;
    const uint4* r2 = T + (size_t)iB.x * 4;
    const uint4* r3 = T + (size_t)iB.y * 4;
    const uint4* r4 = T + (size_t)iC.x * 4;
    const uint4* r5 = T + (size_t)iC.y * 4;

    // float2 index: plane base p*HW/2, odd row base = blk*W + 512, col pair rem2
    size_t obase = (size_t)blk * W + 512 + rem2;
    #pragma unroll
    for (int c = 0; c < 4; ++c) {
        uint4 a = r0[c], b = r1[c], d = r2[c];
        uint4 e = r3[c], g = r4[c], h = r5[c];
        unsigned av[4] = {a.x, a.y, a.z, a.w};
        unsigned bv[4] = {b.x, b.y, b.z, b.w};
        unsigned dv[4] = {d.x, d.y, d.z, d.w};
        unsigned ev[4] = {e.x, e.y, e.z, e.w};
        unsigned gv[4] = {g.x, g.y, g.z, g.w};
        unsigned hv[4] = {h.x, h.y, h.z, h.w};
        #pragma unroll
        for (int j = 0; j < 4; ++j) {
            int p = c * 8 + j * 2;
            float2 lo = make_float2(
                w00*bf_lo(av[j]) + w01*bf_lo(bv[j]) + w02*bf_lo(dv[j]),
                w10*bf_lo(ev[j]) + w11*bf_lo(gv[j]) + w12*bf_lo(hv[j]));
            float2 hi = make_float2(
                w00*bf_hi(av[j]) + w01*bf_hi(bv[j]) + w02*bf_hi(dv[j]),
                w10*bf_hi(ev[j]) + w11*bf_hi(gv[j]) + w12*bf_hi(hv[j]));
            nt_store_f2(lo, out2 + (size_t)p       * (HW/2) + obase);
            nt_store_f2(hi, out2 + (size_t)(p + 1) * (HW/2) + obase);
        }
    }
}

// ---------------------------------------------------------------------------
// Fallback path (R0 kernels) in case ws_size < sizeof(T)
// ---------------------------------------------------------------------------

__global__ void copy_even_rows_kernel(const float4* __restrict__ src,
                                      float4* __restrict__ dst) {
    const int per_plane = (H / 2) * (W / 4);
    int t = blockIdx.x * blockDim.x + threadIdx.x;
    if (t >= NP * per_plane) return;
    int p   = t / per_plane;
    int rem = t - p * per_plane;
    int r2  = rem >> 8;
    int c4  = rem & 255;
    int off = p * (HW / 4) + (r2 * 2) * (W / 4) + c4;
    dst[off] = src[off];
}

__global__ void fill_kernel(const float* __restrict__ coded,
                            const int*   __restrict__ idx,
                            const float* __restrict__ dist,
                            const int*   __restrict__ filled_idx,
                            const int*   __restrict__ unfilled_idx,
                            float* __restrict__ out) {
    int u = blockIdx.x * blockDim.x + threadIdx.x;
    if (u >= U) return;
    int i0 = idx[3*u + 0], i1 = idx[3*u + 1], i2 = idx[3*u + 2];
    float w0 = 1.0f / dist[3*u + 0];
    float w1 = 1.0f / dist[3*u + 1];
    float w2 = 1.0f / dist[3*u + 2];
    float inv = 1.0f / (w0 + w1 + w2);
    w0 *= inv; w1 *= inv; w2 *= inv;
    int n0 = filled_idx[2*i0] * W + filled_idx[2*i0 + 1];
    int n1 = filled_idx[2*i1] * W + filled_idx[2*i1 + 1];
    int n2 = filled_idx[2*i2] * W + filled_idx[2*i2 + 1];
    int uf = unfilled_idx[2*u] * W + unfilled_idx[2*u + 1];
    #pragma unroll 4
    for (int p = 0; p < NP; ++p) {
        const float* pl = coded + (size_t)p * HW;
        out[(size_t)p * HW + uf] = w0 * pl[n0] + w1 * pl[n1] + w2 * pl[n2];
    }
}

// ---------------------------------------------------------------------------

extern "C" void kernel_launch(void* const* d_in, const int* in_sizes, int n_in,
                              void* d_out, int out_size, void* d_ws, size_t ws_size,
                              hipStream_t stream) {
    const float* coded        = (const float*)d_in[0];
    const int*   idx          = (const int*)d_in[1];
    const float* dist         = (const float*)d_in[2];
    const int*   filled_idx   = (const int*)d_in[3];
    const int*   unfilled_idx = (const int*)d_in[4];
    float*       out          = (float*)d_out;

    const size_t t_bytes = (size_t)F * NP * sizeof(unsigned short);   // 16.7 MB

    if (ws_size >= t_bytes) {
        uint4* T = (uint4*)d_ws;
        build_T_kernel<<<(F + 255) / 256, 256, 0, stream>>>(
            (const float2*)coded, T);
        fill_even_kernel<<<(F + 255) / 256, 256, 0, stream>>>(
            idx, dist, T, (float2*)out);
        fill_odd_kernel<<<(F + 255) / 256, 256, 0, stream>>>(
            idx, dist, T, (float2*)out);
    } else {
        const int copy_threads = NP * (H / 2) * (W / 4);
        copy_even_rows_kernel<<<(copy_threads + 255) / 256, 256, 0, stream>>>(
            (const float4*)coded, (float4*)out);
        fill_kernel<<<(U + 255) / 256, 256, 0, stream>>>(
            coded, idx, dist, filled_idx, unfilled_idx, out);
    }
}

// Round 5
// 107.373 us; speedup vs baseline: 1.3443x; 1.3443x over previous
//
#include <hip/hip_runtime.h>
#include <string.h>

// Problem constants (match reference)
static constexpr int H  = 1024, W = 1024, B = 8, C = 4, K = 3;
static constexpr int HW = H * W;
static constexpr int F  = (H / 2) * (W / 2);   // 262144 filled
static constexpr int U  = HW - F;              // 786432 unfilled
static constexpr int NP = B * C;               // 32 planes
static constexpr int U_ODD = (H / 2) * W;      // 524288 odd-row unfilled

// bf16 helpers (RNE round)
__device__ inline unsigned short f2bf(float f) {
    unsigned u = __float_as_uint(f);
    u += 0x7fffu + ((u >> 16) & 1u);
    return (unsigned short)(u >> 16);
}
__device__ inline float bf_lo(unsigned v) { return __uint_as_float(v << 16); }
__device__ inline float bf_hi(unsigned v) { return __uint_as_float(v & 0xffff0000u); }

// non-temporal helpers
__device__ inline void nt_store_f2(float2 v, float2* p) {
    double d;
    memcpy(&d, &v, 8);
    __builtin_nontemporal_store(d, reinterpret_cast<double*>(p));
}

// ---------------------------------------------------------------------------
// Kernel 1: build T[f][32] bf16 (64 B row). No out writes.
// ---------------------------------------------------------------------------
__global__ void build_T_kernel(const float2* __restrict__ src2,
                               uint4* __restrict__ T) {
    int f = blockIdx.x * blockDim.x + threadIdx.x;
    if (f >= F) return;
    int r2 = f >> 9;
    int c2 = f & 511;
    int base = r2 * W + c2;                    // float2 index within a plane
    unsigned packed[NP / 2];
    #pragma unroll
    for (int p = 0; p < NP; p += 2) {
        float2 v0 = src2[(size_t)p * (HW / 2) + base];
        float2 v1 = src2[(size_t)(p + 1) * (HW / 2) + base];
        packed[p / 2] = (unsigned)f2bf(v0.x) | ((unsigned)f2bf(v1.x) << 16);
    }
    uint4* row = T + (size_t)f * 4;
    #pragma unroll
    for (int c = 0; c < 4; ++c)
        row[c] = make_uint4(packed[4*c], packed[4*c+1], packed[4*c+2], packed[4*c+3]);
}

// ---------------------------------------------------------------------------
// Fused fill kernel, U threads total.
//  t < F: even-row pair (filled col 2*rem, unfilled col 2*rem+1) -> float2
//  t >= F: one odd-row pixel -> scalar store (odd rows are 100% unfilled,
//          so a wave's 64 consecutive 4B stores fully cover the lines)
// ---------------------------------------------------------------------------
__global__ void fill_fused_kernel(const int*   __restrict__ idx,
                                  const float* __restrict__ dist,
                                  const uint4* __restrict__ T,
                                  float* __restrict__ out) {
    int t = blockIdx.x * blockDim.x + threadIdx.x;
    if (t >= U) return;

    if (t < F) {
        // ------------------- even-row pair path -------------------
        int blk = t >> 9;          // even row / 2
        int rem = t & 511;         // column pair
        int u = blk * 1536 + rem;  // argwhere order: even block of 512 first

        int i0 = __builtin_nontemporal_load(idx + 3*u + 0);
        int i1 = __builtin_nontemporal_load(idx + 3*u + 1);
        int i2 = __builtin_nontemporal_load(idx + 3*u + 2);
        float w0 = 1.0f / __builtin_nontemporal_load(dist + 3*u + 0);
        float w1 = 1.0f / __builtin_nontemporal_load(dist + 3*u + 1);
        float w2 = 1.0f / __builtin_nontemporal_load(dist + 3*u + 2);
        float inv = 1.0f / (w0 + w1 + w2);
        w0 *= inv; w1 *= inv; w2 *= inv;

        const uint4* r0 = T + (size_t)i0 * 4;
        const uint4* r1 = T + (size_t)i1 * 4;
        const uint4* r2 = T + (size_t)i2 * 4;
        const uint4* rs = T + (size_t)t  * 4;      // self (left filled neighbor)

        float2* out2 = (float2*)out;
        size_t obase = (size_t)blk * W + rem;      // float2 units
        #pragma unroll
        for (int c = 0; c < 4; ++c) {
            uint4 a = r0[c], b = r1[c], d = r2[c], s = rs[c];
            unsigned av[4] = {a.x, a.y, a.z, a.w};
            unsigned bv[4] = {b.x, b.y, b.z, b.w};
            unsigned dv[4] = {d.x, d.y, d.z, d.w};
            unsigned sv[4] = {s.x, s.y, s.z, s.w};
            #pragma unroll
            for (int j = 0; j < 4; ++j) {
                int p = c * 8 + j * 2;
                float2 lo = make_float2(bf_lo(sv[j]),
                    w0*bf_lo(av[j]) + w1*bf_lo(bv[j]) + w2*bf_lo(dv[j]));
                float2 hi = make_float2(bf_hi(sv[j]),
                    w0*bf_hi(av[j]) + w1*bf_hi(bv[j]) + w2*bf_hi(dv[j]));
                nt_store_f2(lo, out2 + (size_t)p       * (HW/2) + obase);
                nt_store_f2(hi, out2 + (size_t)(p + 1) * (HW/2) + obase);
            }
        }
    } else {
        // ------------------- odd-row pixel path -------------------
        int o   = t - F;           // 0 .. U_ODD-1
        int blk = o >> 10;         // odd row = 2*blk+1
        int col = o & 1023;
        int u   = blk * 1536 + 512 + col;
        int uf  = (2 * blk + 1) * W + col;

        int i0 = __builtin_nontemporal_load(idx + 3*u + 0);
        int i1 = __builtin_nontemporal_load(idx + 3*u + 1);
        int i2 = __builtin_nontemporal_load(idx + 3*u + 2);
        float w0 = 1.0f / __builtin_nontemporal_load(dist + 3*u + 0);
        float w1 = 1.0f / __builtin_nontemporal_load(dist + 3*u + 1);
        float w2 = 1.0f / __builtin_nontemporal_load(dist + 3*u + 2);
        float inv = 1.0f / (w0 + w1 + w2);
        w0 *= inv; w1 *= inv; w2 *= inv;

        const uint4* r0 = T + (size_t)i0 * 4;
        const uint4* r1 = T + (size_t)i1 * 4;
        const uint4* r2 = T + (size_t)i2 * 4;
        float* o_ptr = out + uf;
        #pragma unroll
        for (int c = 0; c < 4; ++c) {
            uint4 a = r0[c], b = r1[c], d = r2[c];
            unsigned av[4] = {a.x, a.y, a.z, a.w};
            unsigned bv[4] = {b.x, b.y, b.z, b.w};
            unsigned dv[4] = {d.x, d.y, d.z, d.w};
            #pragma unroll
            for (int j = 0; j < 4; ++j) {
                int p = c * 8 + j * 2;
                float lo = w0*bf_lo(av[j]) + w1*bf_lo(bv[j]) + w2*bf_lo(dv[j]);
                float hi = w0*bf_hi(av[j]) + w1*bf_hi(bv[j]) + w2*bf_hi(dv[j]);
                __builtin_nontemporal_store(lo, o_ptr + (size_t)p       * HW);
                __builtin_nontemporal_store(hi, o_ptr + (size_t)(p + 1) * HW);
            }
        }
    }
}

// ---------------------------------------------------------------------------
// Fallback path (R0 kernels) in case ws_size < sizeof(T)
// ---------------------------------------------------------------------------

__global__ void copy_even_rows_kernel(const float4* __restrict__ src,
                                      float4* __restrict__ dst) {
    const int per_plane = (H / 2) * (W / 4);
    int t = blockIdx.x * blockDim.x + threadIdx.x;
    if (t >= NP * per_plane) return;
    int p   = t / per_plane;
    int rem = t - p * per_plane;
    int r2  = rem >> 8;
    int c4  = rem & 255;
    int off = p * (HW / 4) + (r2 * 2) * (W / 4) + c4;
    dst[off] = src[off];
}

__global__ void fill_kernel(const float* __restrict__ coded,
                            const int*   __restrict__ idx,
                            const float* __restrict__ dist,
                            const int*   __restrict__ filled_idx,
                            const int*   __restrict__ unfilled_idx,
                            float* __restrict__ out) {
    int u = blockIdx.x * blockDim.x + threadIdx.x;
    if (u >= U) return;
    int i0 = idx[3*u + 0], i1 = idx[3*u + 1], i2 = idx[3*u + 2];
    float w0 = 1.0f / dist[3*u + 0];
    float w1 = 1.0f / dist[3*u + 1];
    float w2 = 1.0f / dist[3*u + 2];
    float inv = 1.0f / (w0 + w1 + w2);
    w0 *= inv; w1 *= inv; w2 *= inv;
    int n0 = filled_idx[2*i0] * W + filled_idx[2*i0 + 1];
    int n1 = filled_idx[2*i1] * W + filled_idx[2*i1 + 1];
    int n2 = filled_idx[2*i2] * W + filled_idx[2*i2 + 1];
    int uf = unfilled_idx[2*u] * W + unfilled_idx[2*u + 1];
    #pragma unroll 4
    for (int p = 0; p < NP; ++p) {
        const float* pl = coded + (size_t)p * HW;
        out[(size_t)p * HW + uf] = w0 * pl[n0] + w1 * pl[n1] + w2 * pl[n2];
    }
}

// ---------------------------------------------------------------------------

extern "C" void kernel_launch(void* const* d_in, const int* in_sizes, int n_in,
                              void* d_out, int out_size, void* d_ws, size_t ws_size,
                              hipStream_t stream) {
    const float* coded        = (const float*)d_in[0];
    const int*   idx          = (const int*)d_in[1];
    const float* dist         = (const float*)d_in[2];
    const int*   filled_idx   = (const int*)d_in[3];
    const int*   unfilled_idx = (const int*)d_in[4];
    float*       out          = (float*)d_out;

    const size_t t_bytes = (size_t)F * NP * sizeof(unsigned short);   // 16.7 MB

    if (ws_size >= t_bytes) {
        uint4* T = (uint4*)d_ws;
        build_T_kernel<<<(F + 255) / 256, 256, 0, stream>>>(
            (const float2*)coded, T);
        fill_fused_kernel<<<(U + 255) / 256, 256, 0, stream>>>(
            idx, dist, T, out);
    } else {
        const int copy_threads = NP * (H / 2) * (W / 4);
        copy_even_rows_kernel<<<(copy_threads + 255) / 256, 256, 0, stream>>>(
            (const float4*)coded, (float4*)out);
        fill_kernel<<<(U + 255) / 256, 256, 0, stream>>>(
            coded, idx, dist, filled_idx, unfilled_idx, out);
    }
}